// Round 6
// baseline (259.389 us; speedup 1.0000x reference)
//
#include <hip/hip_runtime.h>
#include <cmath>

#define HH 256
#define WW 256
#define BB 64
#define RR 4                 // tap radius: exp(-12.5)=3.7e-6 dropped -> error ~4e-5 << 0.1 thresh
#define OROWS 16             // output rows per block strip
#define NUNITS (BB * 16)     // 1024 blocks; 5 blocks/CU capacity = 1280 -> all resident + slack

static __device__ __forceinline__ float bin(float v) { return (v > 0.0f) ? 1.0f : 0.0f; }
// bf16 truncation pack (ch4 staging only): rel err <= 0.4% << 0.101 threshold
static __device__ __forceinline__ unsigned pk2(float a, float b) {
    return (__float_as_uint(a) >> 16) | (__float_as_uint(b) & 0xffff0000u);
}
static __device__ __forceinline__ float up_lo(unsigned u) { return __uint_as_float(u << 16); }
static __device__ __forceinline__ float up_hi(unsigned u) { return __uint_as_float(u & 0xffff0000u); }

// ---------------------------------------------------------------------------
// One block per (b, 16-row strip), 192 threads = 3 waves, wave w == map w.
// Each wave, independently (NO barriers in hot path):
//   for each of 24 image rows: 1 coalesced float4 load/lane (lane=4px),
//   binarize, halo via 8 __shfl, 9-tap h-blur in regs, accumulate into
//   acc[16] (64 VGPRs, static idx). Wave max -> atomicMax(bmax[b*3+w]).
// Then per-batch 16-block bounded spin, normalize from regs, write ch(w+1)
// once; t,c staged bf16 in LDS for ch4 = t*c. ch0 copied row-split.
// map 0: x[:,2] s=1.0 -> ch1 ; map 1: x[:,1] -> ch2 ; map 2: x[:,3] s=0.5 -> ch3
// Residency: LB(192,4) -> VGPR<=128 -> 5 blocks/CU (15 waves, 80KB LDS) ->
// 1280 slots >= 1024 grid; spin additionally bounded so no-hang is guaranteed.
// ---------------------------------------------------------------------------
__global__ __launch_bounds__(192, 4) void fused_kernel(const float* __restrict__ x,
                                                       float* __restrict__ out,
                                                       int* __restrict__ ws) {
    __shared__ unsigned mbuf[2][OROWS * 128];   // normalized t,c rows, bf16x2: 16 KB

    int* bmax = ws;                  // [b*3+m] float-as-int maxes (>=0 -> int cmp ok)
    int* cnt  = ws + 192;            // [b] arrival counters (memset 0 per launch)

    // XCD-chunked swizzle: each batch's 16 blocks land on one XCD (L2 + fast spin).
    const int bid = blockIdx.x;
    const int unit = (bid & 7) * (NUNITS >> 3) + (bid >> 3);
    const int b = unit >> 4;
    const int strip = unit & 15;
    const int ti0 = strip * OROWS;
    const int tid = threadIdx.x;
    const int w = tid >> 6;          // wave == map index
    const int l = tid & 63;          // lane: pixels 4l..4l+3

    const int src_c = (w == 0) ? 2 : ((w == 1) ? 1 : 3);
    const float inv2s2 = (w == 2) ? 2.0f : 0.5f;
    float wm[RR + 1];
#pragma unroll
    for (int d = 0; d <= RR; ++d) wm[d] = __expf(-(float)(d * d) * inv2s2);

    // ---- ch0 copy: rows interleaved stride-3 across the 3 waves ----
    {
        const float* x0 = x + (((size_t)b * 4) << 16);
        float* o0 = out + (((size_t)b * 5) << 16);
#pragma unroll
        for (int k = 0; k < 6; ++k) {
            int r = 3 * k + w;
            if (r < OROWS) {
                size_t off = ((size_t)(ti0 + r) << 8) + 4 * l;
                *(float4*)&o0[off] = *(const float4*)&x0[off];
            }
        }
    }

    // ---- splat: 24 rows, register-only pipeline ----
    const float* xc = x + (((size_t)b * 4 + src_c) << 16);
    float4 acc[OROWS];
#pragma unroll
    for (int o = 0; o < OROWS; ++o) acc[o] = make_float4(0.f, 0.f, 0.f, 0.f);

#pragma unroll
    for (int r = 0; r < OROWS + 2 * RR; ++r) {
        const int gi = ti0 + r - RR;           // image row (uniform branch)
        if (gi >= 0 && gi < HH) {
            float4 q = *(const float4*)(xc + ((size_t)gi << 8) + 4 * l);
            float a0 = bin(q.x), a1 = bin(q.y), a2 = bin(q.z), a3 = bin(q.w);
            // halo: lane l-1 pixels (4l-4..4l-1), lane l+1 pixels (4l+4..4l+7)
            float v3 = __shfl_up(a3, 1, 64);   // px 4l-1
            float v2 = __shfl_up(a2, 1, 64);
            float v1 = __shfl_up(a1, 1, 64);
            float v0 = __shfl_up(a0, 1, 64);   // px 4l-4
            float v8 = __shfl_down(a0, 1, 64); // px 4l+4
            float v9 = __shfl_down(a1, 1, 64);
            float v10 = __shfl_down(a2, 1, 64);
            float v11 = __shfl_down(a3, 1, 64);
            if (l == 0)  { v0 = v1 = v2 = v3 = 0.f; }
            if (l == 63) { v8 = v9 = v10 = v11 = 0.f; }
            const float v4 = a0, v5 = a1, v6 = a2, v7 = a3;
            float h0 = wm[4]*(v0+v8)  + wm[3]*(v1+v7)  + wm[2]*(v2+v6) + wm[1]*(v3+v5) + wm[0]*v4;
            float h1 = wm[4]*(v1+v9)  + wm[3]*(v2+v8)  + wm[2]*(v3+v7) + wm[1]*(v4+v6) + wm[0]*v5;
            float h2 = wm[4]*(v2+v10) + wm[3]*(v3+v9)  + wm[2]*(v4+v8) + wm[1]*(v5+v7) + wm[0]*v6;
            float h3 = wm[4]*(v3+v11) + wm[3]*(v4+v10) + wm[2]*(v5+v9) + wm[1]*(v6+v8) + wm[0]*v7;
            // v-accumulate: h-row r feeds out rows o in [r-8, r] with weight wm[|r-4-o|]
#pragma unroll
            for (int o = 0; o < OROWS; ++o) {
                if (o >= r - 2 * RR && o <= r) {       // compile-time (r,o consts)
                    int d = r - RR - o; if (d < 0) d = -d;
                    const float wk = wm[d];
                    acc[o].x += wk * h0; acc[o].y += wk * h1;
                    acc[o].z += wk * h2; acc[o].w += wk * h3;
                }
            }
        }
    }

    // ---- wave max -> atomicMax (wave == map, no cross-wave reduce) ----
    float lmax = 0.f;
#pragma unroll
    for (int o = 0; o < OROWS; ++o)
        lmax = fmaxf(lmax, fmaxf(fmaxf(acc[o].x, acc[o].y), fmaxf(acc[o].z, acc[o].w)));
#pragma unroll
    for (int off = 32; off > 0; off >>= 1)
        lmax = fmaxf(lmax, __shfl_down(lmax, off, 64));
    if (l == 0) atomicMax(&bmax[b * 3 + w], __float_as_int(lmax));

    // ---- per-batch barrier: 16 co-resident sibling blocks, 3 scalars cross.
    //      Bounded spin (constant s_sleep args): no-hang guaranteed.
    __syncthreads();                  // all 3 waves' atomicMax issued before signal
    if (tid == 0) {
        __hip_atomic_fetch_add(&cnt[b], 1, __ATOMIC_ACQ_REL, __HIP_MEMORY_SCOPE_AGENT);
        int it = 0;
        while (__hip_atomic_load(&cnt[b], __ATOMIC_ACQUIRE, __HIP_MEMORY_SCOPE_AGENT) < 16
               && it < (1 << 24)) {
            if (it < 1024) {
                __builtin_amdgcn_s_sleep(2);
            } else {
                __builtin_amdgcn_s_sleep(16);
            }
            ++it;
        }
    }
    __syncthreads();

    float mx = __int_as_float(__hip_atomic_load(&bmax[b * 3 + w], __ATOMIC_RELAXED,
                                                __HIP_MEMORY_SCOPE_AGENT));
    if (mx == 0.f) mx = 1.f;
    const float rm = 1.f / mx;

    // ---- normalize from regs, write own channel; stage t,c to LDS for ch4 ----
    float* oc = out + (((size_t)b * 5 + (w + 1)) << 16);
#pragma unroll
    for (int o = 0; o < OROWS; ++o) {
        float4 t = acc[o];
        t.x *= rm; t.y *= rm; t.z *= rm; t.w *= rm;
        *(float4*)&oc[((size_t)(ti0 + o) << 8) + 4 * l] = t;
        if (w < 2) {
            mbuf[w][o * 128 + 2 * l]     = pk2(t.x, t.y);
            mbuf[w][o * 128 + 2 * l + 1] = pk2(t.z, t.w);
        }
    }
    __syncthreads();

    // ---- ch4 = t*c from staged bf16, rows split stride-3 across waves ----
    float* o4 = out + (((size_t)b * 5 + 4) << 16);
#pragma unroll
    for (int k = 0; k < 6; ++k) {
        int r = 3 * k + w;
        if (r < OROWS) {
            unsigned t01 = mbuf[0][r * 128 + 2 * l], t23 = mbuf[0][r * 128 + 2 * l + 1];
            unsigned c01 = mbuf[1][r * 128 + 2 * l], c23 = mbuf[1][r * 128 + 2 * l + 1];
            float4 mul = make_float4(up_lo(t01) * up_lo(c01), up_hi(t01) * up_hi(c01),
                                     up_lo(t23) * up_lo(c23), up_hi(t23) * up_hi(c23));
            *(float4*)&o4[((size_t)(ti0 + r) << 8) + 4 * l] = mul;
        }
    }
}

extern "C" void kernel_launch(void* const* d_in, const int* in_sizes, int n_in,
                              void* d_out, int out_size, void* d_ws, size_t ws_size,
                              hipStream_t stream) {
    const float* x = (const float*)d_in[0];
    float* out = (float*)d_out;
    int* ws = (int*)d_ws;   // 192 int maxes + 64 int counters = 1024 B

    (void)hipMemsetAsync(d_ws, 0, 1024, stream);   // capture-legal reset of maxes+counters
    hipLaunchKernelGGL(fused_kernel, dim3(NUNITS), dim3(192), 0, stream, x, out, ws);
}

// Round 7
// 252.194 us; speedup vs baseline: 1.0285x; 1.0285x over previous
//
#include <hip/hip_runtime.h>
#include <cmath>

#define HH 256
#define WW 256
#define BB 64
#define RR 4                 // tap radius: exp(-12.5)=3.7e-6 dropped -> error ~4e-5 << 0.1 thresh
#define OROWS 16             // output rows per block strip
#define NUNITS (BB * 16)     // 1024 blocks; residency >= 4 blocks/CU (see launch_bounds note)

static __device__ __forceinline__ float bin(float v) { return (v > 0.0f) ? 1.0f : 0.0f; }
// bf16 truncation pack (ch4 staging only): rel err <= 0.4% << 0.101 threshold
static __device__ __forceinline__ unsigned pk2(float a, float b) {
    return (__float_as_uint(a) >> 16) | (__float_as_uint(b) & 0xffff0000u);
}
static __device__ __forceinline__ float up_lo(unsigned u) { return __uint_as_float(u << 16); }
static __device__ __forceinline__ float up_hi(unsigned u) { return __uint_as_float(u & 0xffff0000u); }

// ---------------------------------------------------------------------------
// One block per (b, 16-row strip), 192 threads = 3 waves, wave w == map w.
// Register-only splat pipeline (no barriers in hot path); per-batch bounded
// spin for the normalization max; single normalized write of ch1..4 + ch0.
//
// r6 post-mortem: __launch_bounds__(192,4) capped VGPR at 128 -> compiler
// SPILLED acc[16] (VGPR_Count=64, WRITE_SIZE 2x output). Now (192,3):
// cap 170. alloc<=128 -> 5 blocks/CU (1280 slots); 129..170 -> 4 blocks/CU
// (1024 slots = grid, still fully resident). Spin bounded as insurance.
// map 0: x[:,2] s=1.0 -> ch1 ; map 1: x[:,1] -> ch2 ; map 2: x[:,3] s=0.5 -> ch3
// ---------------------------------------------------------------------------
__global__ __launch_bounds__(192, 3) void fused_kernel(const float* __restrict__ x,
                                                       float* __restrict__ out,
                                                       int* __restrict__ ws) {
    __shared__ unsigned mbuf[2][OROWS * 128];   // normalized t,c rows, bf16x2: 16 KB

    int* bmax = ws;                  // [b*3+m] float-as-int maxes (>=0 -> int cmp ok)
    int* cnt  = ws + 192;            // [b] arrival counters (memset 0 per launch)

    // XCD-chunked swizzle: each batch's 16 blocks land on one XCD (L2 + fast spin).
    const int bid = blockIdx.x;
    const int unit = (bid & 7) * (NUNITS >> 3) + (bid >> 3);
    const int b = unit >> 4;
    const int strip = unit & 15;
    const int ti0 = strip * OROWS;
    const int tid = threadIdx.x;
    const int w = tid >> 6;          // wave == map index
    const int l = tid & 63;          // lane: pixels 4l..4l+3

    const int src_c = (w == 0) ? 2 : ((w == 1) ? 1 : 3);
    // Hardcoded taps: exp(-d^2/(2 s^2)); s=1.0 for maps 0,1; s=0.5 for map 2.
    const bool hs = (w == 2);
    const float wm[RR + 1] = {
        1.0f,
        hs ? 1.3533528e-1f : 6.0653066e-1f,
        hs ? 3.3546263e-4f : 1.3533528e-1f,
        hs ? 1.5229980e-8f : 1.1108997e-2f,
        hs ? 1.2664166e-14f : 3.3546263e-4f
    };

    // ---- ch0 copy: rows interleaved stride-3 across the 3 waves ----
    {
        const float* x0 = x + (((size_t)b * 4) << 16);
        float* o0 = out + (((size_t)b * 5) << 16);
#pragma unroll
        for (int k = 0; k < 6; ++k) {
            int r = 3 * k + w;
            if (r < OROWS) {
                size_t off = ((size_t)(ti0 + r) << 8) + 4 * l;
                *(float4*)&o0[off] = *(const float4*)&x0[off];
            }
        }
    }

    // ---- splat: 24 rows, register-only pipeline ----
    const float* xc = x + (((size_t)b * 4 + src_c) << 16);
    float4 acc[OROWS];
#pragma unroll
    for (int o = 0; o < OROWS; ++o) acc[o] = make_float4(0.f, 0.f, 0.f, 0.f);

#pragma unroll
    for (int r = 0; r < OROWS + 2 * RR; ++r) {
        const int gi = ti0 + r - RR;           // image row (uniform branch)
        if (gi >= 0 && gi < HH) {
            float4 q = *(const float4*)(xc + ((size_t)gi << 8) + 4 * l);
            float a0 = bin(q.x), a1 = bin(q.y), a2 = bin(q.z), a3 = bin(q.w);
            // halo: lane l-1 pixels (4l-4..4l-1), lane l+1 pixels (4l+4..4l+7)
            float v3 = __shfl_up(a3, 1, 64);   // px 4l-1
            float v2 = __shfl_up(a2, 1, 64);
            float v1 = __shfl_up(a1, 1, 64);
            float v0 = __shfl_up(a0, 1, 64);   // px 4l-4
            float v8 = __shfl_down(a0, 1, 64); // px 4l+4
            float v9 = __shfl_down(a1, 1, 64);
            float v10 = __shfl_down(a2, 1, 64);
            float v11 = __shfl_down(a3, 1, 64);
            if (l == 0)  { v0 = v1 = v2 = v3 = 0.f; }
            if (l == 63) { v8 = v9 = v10 = v11 = 0.f; }
            const float v4 = a0, v5 = a1, v6 = a2, v7 = a3;
            float h0 = wm[4]*(v0+v8)  + wm[3]*(v1+v7)  + wm[2]*(v2+v6) + wm[1]*(v3+v5) + wm[0]*v4;
            float h1 = wm[4]*(v1+v9)  + wm[3]*(v2+v8)  + wm[2]*(v3+v7) + wm[1]*(v4+v6) + wm[0]*v5;
            float h2 = wm[4]*(v2+v10) + wm[3]*(v3+v9)  + wm[2]*(v4+v8) + wm[1]*(v5+v7) + wm[0]*v6;
            float h3 = wm[4]*(v3+v11) + wm[3]*(v4+v10) + wm[2]*(v5+v9) + wm[1]*(v6+v8) + wm[0]*v7;
            // v-accumulate: h-row r feeds out rows o in [r-8, r] with weight wm[|r-4-o|]
#pragma unroll
            for (int o = 0; o < OROWS; ++o) {
                if (o >= r - 2 * RR && o <= r) {       // compile-time (r,o consts)
                    int d = r - RR - o; if (d < 0) d = -d;
                    const float wk = wm[d];
                    acc[o].x += wk * h0; acc[o].y += wk * h1;
                    acc[o].z += wk * h2; acc[o].w += wk * h3;
                }
            }
        }
    }

    // ---- wave max -> atomicMax (wave == map, no cross-wave reduce) ----
    float lmax = 0.f;
#pragma unroll
    for (int o = 0; o < OROWS; ++o)
        lmax = fmaxf(lmax, fmaxf(fmaxf(acc[o].x, acc[o].y), fmaxf(acc[o].z, acc[o].w)));
#pragma unroll
    for (int off = 32; off > 0; off >>= 1)
        lmax = fmaxf(lmax, __shfl_down(lmax, off, 64));
    if (l == 0) atomicMax(&bmax[b * 3 + w], __float_as_int(lmax));

    // ---- per-batch barrier: 16 co-resident sibling blocks, 3 scalars cross.
    //      Bounded spin (constant s_sleep args): no-hang guaranteed.
    __syncthreads();                  // all 3 waves' atomicMax issued before signal
    if (tid == 0) {
        __hip_atomic_fetch_add(&cnt[b], 1, __ATOMIC_ACQ_REL, __HIP_MEMORY_SCOPE_AGENT);
        int it = 0;
        while (__hip_atomic_load(&cnt[b], __ATOMIC_ACQUIRE, __HIP_MEMORY_SCOPE_AGENT) < 16
               && it < (1 << 24)) {
            if (it < 1024) {
                __builtin_amdgcn_s_sleep(2);
            } else {
                __builtin_amdgcn_s_sleep(16);
            }
            ++it;
        }
    }
    __syncthreads();

    float mx = __int_as_float(__hip_atomic_load(&bmax[b * 3 + w], __ATOMIC_RELAXED,
                                                __HIP_MEMORY_SCOPE_AGENT));
    if (mx == 0.f) mx = 1.f;
    const float rm = 1.f / mx;

    // ---- normalize from regs, write own channel; stage t,c to LDS for ch4 ----
    float* oc = out + (((size_t)b * 5 + (w + 1)) << 16);
#pragma unroll
    for (int o = 0; o < OROWS; ++o) {
        float4 t = acc[o];
        t.x *= rm; t.y *= rm; t.z *= rm; t.w *= rm;
        *(float4*)&oc[((size_t)(ti0 + o) << 8) + 4 * l] = t;
        if (w < 2) {
            mbuf[w][o * 128 + 2 * l]     = pk2(t.x, t.y);
            mbuf[w][o * 128 + 2 * l + 1] = pk2(t.z, t.w);
        }
    }
    __syncthreads();

    // ---- ch4 = t*c from staged bf16, rows split stride-3 across waves ----
    float* o4 = out + (((size_t)b * 5 + 4) << 16);
#pragma unroll
    for (int k = 0; k < 6; ++k) {
        int r = 3 * k + w;
        if (r < OROWS) {
            unsigned t01 = mbuf[0][r * 128 + 2 * l], t23 = mbuf[0][r * 128 + 2 * l + 1];
            unsigned c01 = mbuf[1][r * 128 + 2 * l], c23 = mbuf[1][r * 128 + 2 * l + 1];
            float4 mul = make_float4(up_lo(t01) * up_lo(c01), up_hi(t01) * up_hi(c01),
                                     up_lo(t23) * up_lo(c23), up_hi(t23) * up_hi(c23));
            *(float4*)&o4[((size_t)(ti0 + r) << 8) + 4 * l] = mul;
        }
    }
}

extern "C" void kernel_launch(void* const* d_in, const int* in_sizes, int n_in,
                              void* d_out, int out_size, void* d_ws, size_t ws_size,
                              hipStream_t stream) {
    const float* x = (const float*)d_in[0];
    float* out = (float*)d_out;
    int* ws = (int*)d_ws;   // 192 int maxes + 64 int counters = 1024 B

    (void)hipMemsetAsync(d_ws, 0, 1024, stream);   // capture-legal reset of maxes+counters
    hipLaunchKernelGGL(fused_kernel, dim3(NUNITS), dim3(192), 0, stream, x, out, ws);
}